// Round 4
// baseline (422.323 us; speedup 1.0000x reference)
//
#include <hip/hip_runtime.h>
#include <hip/hip_bf16.h>

#define BB 2
#define LL 384
#define DD 128
#define NH 8

typedef const float* fp32p;

// ---------------- K1: projections + point rotation ----------------
// grid 768 (b*L+l), block 128
__global__ __launch_bounds__(128) void k_proj(
    fp32p x, fp32p r, fp32p tvec,
    fp32p Wqs, fp32p Wks, fp32p Wvs,
    fp32p Wqp, fp32p Wkp, fp32p Wvp,
    float* qs, float* ks, float* vs,
    float* qp, float* kp, float* vp)
{
  int bl = blockIdx.x;
  int t = threadIdx.x;
  __shared__ float xs[128];
  __shared__ float yq[96], yk[96], yv[96];
  xs[t] = x[bl*128 + t];
  __syncthreads();
  float aq = 0.f, ak = 0.f, av = 0.f;
  for (int d = 0; d < 128; ++d) {
    float xv = xs[d];
    aq += xv * Wqs[d*128 + t];
    ak += xv * Wks[d*128 + t];
    av += xv * Wvs[d*128 + t];
  }
  int b = bl / LL, l = bl - (bl / LL) * LL;
  int n = t >> 4, dhs = t & 15;
  int rowbase = (b*NH + n)*LL + l;
  qs[rowbase*16 + dhs] = aq;
  ks[rowbase*16 + dhs] = ak;
  vs[rowbase*16 + dhs] = av;
  if (t < 96) {
    float pq = 0.f, pk = 0.f, pv = 0.f;
    for (int d = 0; d < 128; ++d) {
      float xv = xs[d];
      pq += xv * Wqp[d*96 + t];
      pk += xv * Wkp[d*96 + t];
      pv += xv * Wvp[d*96 + t];
    }
    yq[t] = pq; yk[t] = pk; yv[t] = pv;
  }
  __syncthreads();
  if (t < 96) {
    int np = t / 12;
    int rem = t - np*12;
    int p = rem / 3, c = rem - p*3;
    float rr0 = r[(bl*3 + 0)*3 + c];
    float rr1 = r[(bl*3 + 1)*3 + c];
    float rr2 = r[(bl*3 + 2)*3 + c];
    float tt  = tvec[bl*3 + c];
    int base = np*12 + p*3;
    int prow = (b*NH + np)*LL + l;
    qp[prow*12 + p*3 + c] = yq[base]*rr0 + yq[base+1]*rr1 + yq[base+2]*rr2 + tt;
    kp[prow*12 + p*3 + c] = yk[base]*rr0 + yk[base+1]*rr1 + yk[base+2]*rr2 + tt;
    vp[prow*12 + p*3 + c] = yv[base]*rr0 + yv[base+1]*rr1 + yv[base+2]*rr2 + tt;
  }
}

// ---------------- K2: bias_pair = e @ Wb  (writes (B,N,L,L) fp32) ----------------
// one thread per (b,i,j); grid 1152, block 256
__global__ __launch_bounds__(256) void k_bias(fp32p e, fp32p Wb, float* bias)
{
  __shared__ float WbS[128*8];
  for (int idx = threadIdx.x; idx < 1024; idx += 256) WbS[idx] = Wb[idx];
  __syncthreads();
  int tid = blockIdx.x*256 + threadIdx.x;          // enumerates (b,i,j)
  int b = tid / (LL*LL);
  int rem = tid - b*(LL*LL);
  int i = rem / LL, j = rem - (rem / LL)*LL;
  const float4* erow = reinterpret_cast<const float4*>(e) + (size_t)tid * 32;
  float acc[8] = {0,0,0,0,0,0,0,0};
  for (int it = 0; it < 32; ++it) {
    float4 v4 = erow[it];
    float vv[4] = {v4.x, v4.y, v4.z, v4.w};
    #pragma unroll
    for (int k = 0; k < 4; ++k) {
      float v = vv[k];
      const float* wr = &WbS[(it*4 + k)*8];
      #pragma unroll
      for (int nn = 0; nn < 8; ++nn) acc[nn] += v * wr[nn];
    }
  }
  #pragma unroll
  for (int nn = 0; nn < 8; ++nn)
    bias[(((size_t)(b*NH + nn)*LL + i)*LL) + j] = acc[nn];
}

// ---------------- K3: logits + softmax (in-place bias -> attn) ----------------
// one wave per (b,n,i); grid 1536, block 256 (4 waves)
__global__ __launch_bounds__(256) void k_attn(
    const float* qs, const float* ks, const float* qp, const float* kp,
    fp32p gamma, float* attn)
{
  int row = blockIdx.x*4 + (threadIdx.x >> 6);     // (b,n,i)
  int lane = threadIdx.x & 63;
  int bn = row / LL;
  int n = bn & 7;
  int rowbase = bn * LL;
  float q[16];
  const float4* q4 = reinterpret_cast<const float4*>(qs + (size_t)row*16);
  #pragma unroll
  for (int k2 = 0; k2 < 4; ++k2) { float4 v = q4[k2]; q[4*k2]=v.x; q[4*k2+1]=v.y; q[4*k2+2]=v.z; q[4*k2+3]=v.w; }
  float qpv[12];
  const float4* p4 = reinterpret_cast<const float4*>(qp + (size_t)row*12);
  #pragma unroll
  for (int k2 = 0; k2 < 3; ++k2) { float4 v = p4[k2]; qpv[4*k2]=v.x; qpv[4*k2+1]=v.y; qpv[4*k2+2]=v.z; qpv[4*k2+3]=v.w; }
  float qq = 0.f;
  #pragma unroll
  for (int k2 = 0; k2 < 12; ++k2) qq += qpv[k2]*qpv[k2];
  float coef = -0.125f * gamma[n];
  float lg[6];
  float* arow = attn + (size_t)row*LL;
  #pragma unroll
  for (int jj = 0; jj < 6; ++jj) {
    int j = lane + jj*64;
    const float4* k4 = reinterpret_cast<const float4*>(ks + (size_t)(rowbase + j)*16);
    float dots = 0.f;
    #pragma unroll
    for (int k2 = 0; k2 < 4; ++k2) { float4 v = k4[k2]; dots += q[4*k2]*v.x + q[4*k2+1]*v.y + q[4*k2+2]*v.z + q[4*k2+3]*v.w; }
    const float4* kp4 = reinterpret_cast<const float4*>(kp + (size_t)(rowbase + j)*12);
    float cross = 0.f, kk = 0.f;
    #pragma unroll
    for (int k2 = 0; k2 < 3; ++k2) {
      float4 v = kp4[k2];
      cross += qpv[4*k2]*v.x + qpv[4*k2+1]*v.y + qpv[4*k2+2]*v.z + qpv[4*k2+3]*v.w;
      kk += v.x*v.x + v.y*v.y + v.z*v.z + v.w*v.w;
    }
    float bs = arow[j];
    lg[jj] = 0.57735027f * (0.25f*dots + bs + coef*(qq + kk - 2.f*cross));
  }
  float m = lg[0];
  #pragma unroll
  for (int jj = 1; jj < 6; ++jj) m = fmaxf(m, lg[jj]);
  #pragma unroll
  for (int off = 32; off >= 1; off >>= 1) m = fmaxf(m, __shfl_xor(m, off, 64));
  float el[6]; float s = 0.f;
  #pragma unroll
  for (int jj = 0; jj < 6; ++jj) { el[jj] = __expf(lg[jj] - m); s += el[jj]; }
  #pragma unroll
  for (int off = 32; off >= 1; off >>= 1) s += __shfl_xor(s, off, 64);
  float inv = 1.f / s;
  #pragma unroll
  for (int jj = 0; jj < 6; ++jj) arow[lane + jj*64] = el[jj]*inv;
}

// ---------------- K4a: out_scalar = attn@vs, op = attn@vp ----------------
// thread per (row, dim32); grid 768, block 256
__global__ __launch_bounds__(256) void k_av(
    const float* attn, const float* vs, const float* vp, float* cat, float* opb)
{
  int tid = blockIdx.x*256 + threadIdx.x;
  int row = tid >> 5;
  int dim = tid & 31;
  if (dim >= 28) return;
  int i = row % LL;
  int bn = row / LL;
  int rowbase = bn * LL;
  const float* arow = attn + (size_t)row*LL;
  const float* src; int stride;
  if (dim < 16) { src = vs + (size_t)rowbase*16 + dim; stride = 16; }
  else          { src = vp + (size_t)rowbase*12 + (dim - 16); stride = 12; }
  float acc = 0.f;
  for (int j = 0; j < LL; ++j) acc += arow[j] * src[(size_t)j*stride];
  int b = bn >> 3, n = bn & 7;
  if (dim < 16) cat[((size_t)(b*LL + i))*1280 + n*16 + dim] = acc;
  else          opb[(size_t)row*12 + (dim - 16)] = acc;
}

// ---------------- K4b: out_pair = attn . e   (block per (b,i)) ----------------
__global__ __launch_bounds__(256) void k_pair(fp32p e, const float* attn, float* cat)
{
  int bi = blockIdx.x;                 // b*L + i
  int b = bi / LL, i = bi - (bi / LL)*LL;
  __shared__ float attnS[8*384];
  __shared__ float redS[128*9];
  for (int idx = threadIdx.x; idx < 8*384; idx += 256) {
    int n = idx / 384, j = idx - n*384;
    attnS[idx] = attn[(((size_t)(b*NH + n)*LL + i)*LL) + j];
  }
  __syncthreads();
  int t = threadIdx.x;
  int oct = t & 15;                    // which 8-float chunk of d
  int n = (t >> 4) & 7;
  int half = t >> 7;
  const float4* ebase = reinterpret_cast<const float4*>(e) + (size_t)bi*LL*32;
  const float* an = attnS + n*384;
  float acc[8] = {0,0,0,0,0,0,0,0};
  for (int jj = 0; jj < 192; ++jj) {
    int j = 2*jj + half;
    float4 va = ebase[j*32 + oct*2];
    float4 vb = ebase[j*32 + oct*2 + 1];
    float a = an[j];
    acc[0] += a * va.x; acc[1] += a * va.y; acc[2] += a * va.z; acc[3] += a * va.w;
    acc[4] += a * vb.x; acc[5] += a * vb.y; acc[6] += a * vb.z; acc[7] += a * vb.w;
  }
  if (half) {
    #pragma unroll
    for (int k = 0; k < 8; ++k) redS[(t - 128)*9 + k] = acc[k];
  }
  __syncthreads();
  if (!half) {
    float* dst = cat + (size_t)bi*1280 + 128 + n*128 + oct*8;
    #pragma unroll
    for (int k = 0; k < 8; ++k) dst[k] = acc[k] + redS[t*9 + k];
  }
}

// ---------------- K5: inverse point transform + norms ----------------
// thread per (row, p); grid 96, block 256
// op_local[c] = sum_k (op - t)[k] * r[b,i,c,k]   (einsum 'bnipk,bick->bnipc')
__global__ __launch_bounds__(256) void k_pt(const float* opb, fp32p r, fp32p tvec, float* cat)
{
  int tid = blockIdx.x*256 + threadIdx.x;    // 24576
  int p = tid & 3;
  int row = tid >> 2;
  int i = row % LL;
  int bn = row / LL;
  int b = bn >> 3, n = bn & 7;
  int bi = b*LL + i;
  float o[3];
  #pragma unroll
  for (int k = 0; k < 3; ++k)
    o[k] = opb[(size_t)row*12 + p*3 + k] - tvec[bi*3 + k];
  float loc[3];
  #pragma unroll
  for (int c = 0; c < 3; ++c) {
    float s = 0.f;
    #pragma unroll
    for (int k = 0; k < 3; ++k) s += o[k] * r[(bi*3 + c)*3 + k];   // r[b,i,c,k]
    loc[c] = s;
  }
  float* dst = cat + (size_t)bi*1280;
  dst[1152 + n*12 + p*3 + 0] = loc[0];
  dst[1152 + n*12 + p*3 + 1] = loc[1];
  dst[1152 + n*12 + p*3 + 2] = loc[2];
  dst[1248 + n*4 + p] = sqrtf(loc[0]*loc[0] + loc[1]*loc[1] + loc[2]*loc[2]);
}

// ---------------- K6: out = cat @ Wo + bo  -> fp32 ----------------
// block per 4 rows; grid 192, block 128
__global__ __launch_bounds__(128) void k_out(const float* cat, fp32p Wo, fp32p bo,
                                             float* out)
{
  __shared__ float catS[4*1280];
  int row0 = blockIdx.x*4;
  for (int idx = threadIdx.x; idx < 4*1280; idx += 128)
    catS[idx] = cat[(size_t)row0*1280 + idx];
  __syncthreads();
  int t = threadIdx.x;
  float bov = bo[t];
  float a0 = bov, a1 = bov, a2 = bov, a3 = bov;
  for (int k = 0; k < 1280; ++k) {
    float w = Wo[k*128 + t];
    a0 += catS[k]        * w;
    a1 += catS[1280 + k] * w;
    a2 += catS[2560 + k] * w;
    a3 += catS[3840 + k] * w;
  }
  out[(size_t)(row0 + 0)*128 + t] = a0;
  out[(size_t)(row0 + 1)*128 + t] = a1;
  out[(size_t)(row0 + 2)*128 + t] = a2;
  out[(size_t)(row0 + 3)*128 + t] = a3;
}

extern "C" void kernel_launch(void* const* d_in, const int* in_sizes, int n_in,
                              void* d_out, int out_size, void* d_ws, size_t ws_size,
                              hipStream_t stream)
{
  fp32p x    = (fp32p)d_in[0];
  fp32p e    = (fp32p)d_in[1];
  fp32p r    = (fp32p)d_in[2];
  fp32p tv   = (fp32p)d_in[3];
  fp32p Wqs  = (fp32p)d_in[4];
  fp32p Wks  = (fp32p)d_in[5];
  fp32p Wvs  = (fp32p)d_in[6];
  fp32p Wb   = (fp32p)d_in[7];
  fp32p Wqp  = (fp32p)d_in[8];
  fp32p Wkp  = (fp32p)d_in[9];
  fp32p Wvp  = (fp32p)d_in[10];
  fp32p gam  = (fp32p)d_in[11];
  fp32p Wo   = (fp32p)d_in[12];
  fp32p bo   = (fp32p)d_in[13];
  float* out = (float*)d_out;

  // ws partition (floats); total ~15.7 MB
  float* qs   = (float*)d_ws;
  float* ks   = qs + 98304;            // 6144*16
  float* vs   = ks + 98304;
  float* qp   = vs + 98304;            // 6144*12
  float* kp   = qp + 73728;
  float* vp   = kp + 73728;
  float* attn = vp + 73728;            // 2*8*384*384 (bias written here, softmaxed in place)
  float* opb  = attn + 2359296;        // 6144*12
  float* cat  = opb + 73728;           // 768*1280

  k_proj<<<768, 128, 0, stream>>>(x, r, tv, Wqs, Wks, Wvs, Wqp, Wkp, Wvp,
                                  qs, ks, vs, qp, kp, vp);
  k_bias<<<1152, 256, 0, stream>>>(e, Wb, attn);
  k_attn<<<1536, 256, 0, stream>>>(qs, ks, qp, kp, gam, attn);
  k_av<<<768, 256, 0, stream>>>(attn, vs, vp, cat, opb);
  k_pair<<<768, 256, 0, stream>>>(e, attn, cat);
  k_pt<<<96, 256, 0, stream>>>(opb, r, tv, cat);
  k_out<<<192, 128, 0, stream>>>(cat, Wo, bo, out);
}